// Round 7
// baseline (265.089 us; speedup 1.0000x reference)
//
#include <hip/hip_runtime.h>

typedef __attribute__((ext_vector_type(8))) short short8;
typedef __attribute__((ext_vector_type(4))) float floatx4;

#define MFMA16(a, b, c) __builtin_amdgcn_mfma_f32_16x16x32_bf16(a, b, c, 0, 0, 0)

__device__ __forceinline__ short f2bf(float f) {
    unsigned int u = __float_as_uint(f);
    u = u + 0x7fffu + ((u >> 16) & 1u);
    return (short)(u >> 16);
}

__device__ __forceinline__ void ldst16(const void* g, void* l) {
    __builtin_amdgcn_global_load_lds(
        (const __attribute__((address_space(1))) void*)g,
        (__attribute__((address_space(3))) void*)l, 16, 0, 0);
}

// ---------------------------------------------------------------------------
// Kernel 0: convert Wq/Wk/Wv fp32 [1024][128] -> bf16 in MFMA FRAGMENT ORDER:
// wtf[which][ks(32)][nt(8)][lane(64)][e(8)], value = W[k][n] with
// n = 16*nt + (lane&15), k = 32*ks + 8*(lane>>4) + e.  A wave's B-fragment
// load is then ONE coalesced 1KB block (base + lane*16B): no gather, no LDS.
// ---------------------------------------------------------------------------
__global__ __launch_bounds__(256) void wconv_kernel(const float* __restrict__ Wq,
                                                    const float* __restrict__ Wk,
                                                    const float* __restrict__ Wv,
                                                    short* __restrict__ wtf) {
    int idx = blockIdx.x * 256 + threadIdx.x;   // < 3*131072
    int w = idx >> 17;
    int rem = idx & 131071;
    int ks = rem >> 12;
    int r2 = rem & 4095;
    int nt = r2 >> 9;
    int r3 = r2 & 511;
    int lane = r3 >> 3, e = r3 & 7;
    int q4 = lane >> 4, l16 = lane & 15;
    int n = 16 * nt + l16;
    int k = 32 * ks + 8 * q4 + e;
    const float* W = (w == 0) ? Wq : (w == 1) ? Wk : Wv;
    wtf[idx] = f2bf(W[k * 128 + n]);
}

// ---------------------------------------------------------------------------
// Kernel 1 (fused q/k/v): C = A[16384x1024](f32) * W (+bias) -> bf16.
// v7 = v6 + T3/T4 counted-vmcnt pipeline (m233: the 2-phase __syncthreads
// structure's vmcnt(0) drain is ~72% of critical path; m218: counted vmcnt
// = +38-73%). Per chunk: issue stage(k+1)[4 DMA] + B(k+1)[8 L2 loads],
// s_waitcnt vmcnt(12) (stage(k)/B(k) retired, next 12 ops stay in flight,
// NEVER 0 in-loop), raw s_barrier, compute (no vmem inside), raw s_barrier.
// B regs double-banked with static names (2x manual unroll). T5 setprio
// around the MFMA cluster. Grid (256,3)=768 blocks = 3/CU, 32KB LDS.
// ---------------------------------------------------------------------------
__global__ __launch_bounds__(256, 3) void proj_kernel(const float* __restrict__ Q,
                                                      const float* __restrict__ K,
                                                      const float* __restrict__ V,
                                                      const short* __restrict__ wtf,
                                                      const float* __restrict__ bq,
                                                      const float* __restrict__ bk,
                                                      const float* __restrict__ bv,
                                                      short* __restrict__ qo,
                                                      short* __restrict__ ko,
                                                      short* __restrict__ vo) {
    alignas(16) __shared__ float Asl[2][64 * 64];  // 16KB/buf: [row][16 slots], pos=c^(r&15)
    const int t = threadIdx.x;                    // 0..255
    const int wv = t >> 6, L = t & 63;
    const int wm = wv >> 1, wn = wv & 1;          // 2x2 wave grid
    const int q4 = L >> 4, l16 = L & 15;
    const int which = blockIdx.y;
    const float* A = (which == 0) ? Q : (which == 1) ? K : V;
    const short* Wf = wtf + which * 131072;
    const float* bias = (which == 0) ? bq : (which == 1) ? bk : bv;
    const int m0 = blockIdx.x * 64;

    floatx4 acc[2][4];
#pragma unroll
    for (int rg = 0; rg < 2; rg++)
#pragma unroll
        for (int nt = 0; nt < 4; nt++) acc[rg][nt] = (floatx4)0.0f;

    auto stage = [&](int buf, int k0) {
        // A tile 64x64 f32 = 1024 slots16 / 256 thr = 4 issues.
        // Dest linear; source col pre-swizzled: LDS[r][c] = A[r][(c^(r&15))*4..]
#pragma unroll
        for (int j = 0; j < 4; j++) {
            int s = j * 256 + t;
            int r = s >> 4, c = (s & 15) ^ (r & 15);
            ldst16(A + (size_t)(m0 + r) * 1024 + k0 + (c << 2),
                   &Asl[buf][(j * 256 + 64 * wv) * 4]);
        }
    };

    auto loadB = [&](int kc, short8 (&dst)[2][4]) {
#pragma unroll
        for (int ks = 0; ks < 2; ks++)
#pragma unroll
            for (int nt = 0; nt < 4; nt++)
                dst[ks][nt] = *(const short8*)(Wf +
                    (((size_t)(2 * kc + ks) * 8 + 4 * wn + nt) * 64 + L) * 8);
    };

    auto computeC = [&](int kc, short8 (&bfr)[2][4]) {
        short8 af[2][2];
#pragma unroll
        for (int rg = 0; rg < 2; rg++)
#pragma unroll
            for (int ks = 0; ks < 2; ks++) {
                int r = 32 * wm + 16 * rg + l16;  // r&15 == l16
                int c0 = 8 * ks + 2 * q4;
                float4 f0 = *(float4*)&Asl[kc & 1][(r * 16 + (c0 ^ l16)) * 4];
                float4 f1 = *(float4*)&Asl[kc & 1][(r * 16 + ((c0 + 1) ^ l16)) * 4];
                short8 v;
                v[0] = f2bf(f0.x); v[1] = f2bf(f0.y); v[2] = f2bf(f0.z); v[3] = f2bf(f0.w);
                v[4] = f2bf(f1.x); v[5] = f2bf(f1.y); v[6] = f2bf(f1.z); v[7] = f2bf(f1.w);
                af[rg][ks] = v;
            }
        __builtin_amdgcn_s_setprio(1);
#pragma unroll
        for (int ks = 0; ks < 2; ks++)
#pragma unroll
            for (int nt = 0; nt < 4; nt++) {
                acc[0][nt] = MFMA16(af[0][ks], bfr[ks][nt], acc[0][nt]);
                acc[1][nt] = MFMA16(af[1][ks], bfr[ks][nt], acc[1][nt]);
            }
        __builtin_amdgcn_s_setprio(0);
    };

    short8 bA[2][4], bB[2][4];

#define PROJ_STEP(KC, BUSE, BLOAD)                                          \
    {                                                                       \
        if ((KC) + 1 < 16) {                                                \
            stage(((KC) + 1) & 1, ((KC) + 1) * 64);                         \
            loadB((KC) + 1, BLOAD);                                         \
            asm volatile("s_waitcnt vmcnt(12)" ::: "memory");               \
        } else {                                                            \
            asm volatile("s_waitcnt vmcnt(0)" ::: "memory");                \
        }                                                                   \
        __builtin_amdgcn_s_barrier();                                       \
        __builtin_amdgcn_sched_barrier(0);                                  \
        computeC((KC), BUSE);                                               \
        __builtin_amdgcn_sched_barrier(0);                                  \
        __builtin_amdgcn_s_barrier();                                       \
    }

    stage(0, 0);          // prologue: chunk 0 DMA + B(0) in flight
    loadB(0, bA);

    for (int kc = 0; kc < 16; kc += 2) {
        PROJ_STEP(kc, bA, bB);
        PROJ_STEP(kc + 1, bB, bA);
    }
#undef PROJ_STEP

#pragma unroll
    for (int rg = 0; rg < 2; rg++) {
        const int rbase = m0 + 32 * wm + 16 * rg + q4 * 4;  // C/D: row=(lane>>4)*4+r
#pragma unroll
        for (int nt = 0; nt < 4; nt++) {
            const int col = 64 * wn + 16 * nt + l16;        // C/D: col=lane&15
            float bvv = bias[col];
#pragma unroll
            for (int r = 0; r < 4; r++) {
                short h = f2bf(acc[rg][nt][r] + bvv);
                int grow = rbase + r;
                if (which == 0) {
                    qo[(size_t)grow * 128 + col] = h;
                } else if (which == 1) {
                    ko[(size_t)grow * 128 + col] = h;
                } else {
                    int bb = grow >> 11, s = grow & 2047;
                    vo[(size_t)bb * 262144 + (size_t)col * 2048 + s] = h;
                }
            }
        }
    }
}

// ---------------------------------------------------------------------------
// Kernel 2: flash attention, fixed-offset softmax (scores bounded; see r0).
// v7 = v6 structure (512 thr = 2 kv-pairs x 4 q-waves, K/V dbuf, batch->XCD
// swizzle) + counted-vmcnt pipeline: per iter, stage(t+1)[8 DMA] ->
// s_waitcnt vmcnt(8) (stage(t) retired, next tile stays in flight) -> raw
// s_barrier -> compute (LDS-only) -> raw s_barrier. One full compute phase
// (~2-3K cyc) of DMA lead >> L2 latency. LDS 146KB, 1 block/CU.
// ---------------------------------------------------------------------------
__global__ __launch_bounds__(512, 2) void flash_kernel(const short* __restrict__ qw,
                                                       const short* __restrict__ kw,
                                                       const short* __restrict__ vw,
                                                       float* __restrict__ out) {
    alignas(16) __shared__ short Kls[2][2][64 * 128];   // [buf][pair], pos=c^(r&15)
    alignas(16) __shared__ short Vls[2][2][128 * 64];   // [buf][pair], pos=c^(r&7)
    alignas(16) __shared__ short Pl[2][64][72];         // [pair][q][kv] (+8 pad)
    const int t = threadIdx.x;                       // 0..511
    const int wvi = t >> 6, L = t & 63;
    const int pr = wvi >> 2, wq = wvi & 3;           // pair, wave-in-pair
    const int pt = t & 255;                          // thread-in-pair
    const int q4 = L >> 4, l16 = L & 15;
    const int bid = blockIdx.x;
    const int b = bid & 7, bq = bid >> 3;            // batch->XCD affinity
    const short* qp = qw + (size_t)b * 262144 + (size_t)bq * 64 * 128;
    const short* kp = kw + (size_t)b * 262144;
    const short* vp = vw + (size_t)b * 262144;

    // Q-frags: wave-private, direct from global (row = 16*wq + l16)
    short8 qf[4];
#pragma unroll
    for (int ks = 0; ks < 4; ks++)
        qf[ks] = *(const short8*)(qp + (16 * wq + l16) * 128 + ks * 32 + q4 * 8);

    floatx4 oacc[8];
#pragma unroll
    for (int dt = 0; dt < 8; dt++) oacc[dt] = (floatx4)0.0f;
    float ps[4] = {0.f, 0.f, 0.f, 0.f};              // distributed row sums
    const float SL = (float)(0.08838834764831845 * 1.4426950408889634); // 1/sqrt(128)*log2(e)

    auto stage = [&](int buf, int kt) {
        const int kv0 = pr * 1024 + kt * 64;
        // K-tile 64x128 (16KB, pair-private): 1024 slots / 256 thr = 4 issues
#pragma unroll
        for (int j = 0; j < 4; j++) {
            int s = j * 256 + pt;
            int r = s >> 4, c = (s & 15) ^ (r & 15);
            ldst16(kp + (size_t)(kv0 + r) * 128 + c * 8,
                   &Kls[buf][pr][(j * 256 + 64 * wq) * 8]);
        }
        // V-tile 128x64 (pre-transposed vt): 1024 slots
#pragma unroll
        for (int j = 0; j < 4; j++) {
            int s = j * 256 + pt;
            int r = s >> 3, c = (s & 7) ^ (r & 7);
            ldst16(vp + (size_t)r * 2048 + kv0 + c * 8,
                   &Vls[buf][pr][(j * 256 + 64 * wq) * 8]);
        }
    };

    stage(0, 0);                                     // prologue DMA

    int cur = 0;
    for (int kt = 0; kt < 16; kt++) {
        if (kt + 1 < 16) {
            stage(cur ^ 1, kt + 1);                  // 8 DMA, stays in flight
            asm volatile("s_waitcnt vmcnt(8)" ::: "memory");   // stage(kt) landed
        } else {
            asm volatile("s_waitcnt vmcnt(0)" ::: "memory");
        }
        __builtin_amdgcn_s_barrier();                // ready: all waves' stage(kt) done
        __builtin_amdgcn_sched_barrier(0);

        // S = Q K^T  (16 q-rows x 64 kv per wave)
        floatx4 sa[4];
        __builtin_amdgcn_s_setprio(1);
#pragma unroll
        for (int nt = 0; nt < 4; nt++) {
            sa[nt] = (floatx4)0.0f;
#pragma unroll
            for (int ks = 0; ks < 4; ks++) {
                short8 bfr = *(short8*)&Kls[cur][pr][(16 * nt + l16) * 128 + ((4 * ks + q4) ^ l16) * 8];
                sa[nt] = MFMA16(qf[ks], bfr, sa[nt]);
            }
        }
        __builtin_amdgcn_s_setprio(0);

        // fixed-offset softmax: p = exp2(s*SL - 4); accumulate per-lane sums
#pragma unroll
        for (int nt = 0; nt < 4; nt++) {
#pragma unroll
            for (int r = 0; r < 4; r++) {
                float pv = __builtin_amdgcn_exp2f(sa[nt][r] * SL - 4.0f);
                ps[r] += pv;
                Pl[pr][16 * wq + q4 * 4 + r][16 * nt + l16] = f2bf(pv);
            }
        }

        // O += P V
        short8 pf0 = *(short8*)&Pl[pr][16 * wq + l16][q4 * 8];
        short8 pf1 = *(short8*)&Pl[pr][16 * wq + l16][32 + q4 * 8];
        __builtin_amdgcn_s_setprio(1);
#pragma unroll
        for (int dt = 0; dt < 8; dt++) {
            short8 v0 = *(short8*)&Vls[cur][pr][(16 * dt + l16) * 64 + (q4 ^ (l16 & 7)) * 8];
            short8 v1 = *(short8*)&Vls[cur][pr][(16 * dt + l16) * 64 + ((4 + q4) ^ (l16 & 7)) * 8];
            oacc[dt] = MFMA16(pf0, v0, oacc[dt]);
            oacc[dt] = MFMA16(pf1, v1, oacc[dt]);
        }
        __builtin_amdgcn_s_setprio(0);

        __builtin_amdgcn_sched_barrier(0);
        __builtin_amdgcn_s_barrier();                // release buf cur for stage(kt+2)
        cur ^= 1;
    }

    // one shuffle-reduce at the end: sum ps over the 16 col-lanes per row group
#pragma unroll
    for (int r = 0; r < 4; r++)
#pragma unroll
        for (int off = 1; off <= 8; off <<= 1)
            ps[r] += __shfl_xor(ps[r], off, 64);

    // ---- merge the two kv-halves (plain sums; no max needed) ----
    __syncthreads();
    float* Om = (float*)&Kls[0][0][0];  // 64x128 f32 = 32KB (= Kls buf0)
    float* Lm = (float*)&Vls[0][0][0];  // 64 floats
    if (pr == 1) {
#pragma unroll
        for (int dt = 0; dt < 8; dt++)
#pragma unroll
            for (int r = 0; r < 4; r++)
                Om[(16 * wq + q4 * 4 + r) * 128 + 16 * dt + l16] = oacc[dt][r];
        if (l16 == 0)
#pragma unroll
            for (int r = 0; r < 4; r++)
                Lm[16 * wq + q4 * 4 + r] = ps[r];
    }
    __syncthreads();
    if (pr == 0) {
        float inv[4];
#pragma unroll
        for (int r = 0; r < 4; r++)
            inv[r] = 1.0f / (ps[r] + Lm[16 * wq + q4 * 4 + r]);
#pragma unroll
        for (int dt = 0; dt < 8; dt++) {
#pragma unroll
            for (int r = 0; r < 4; r++) {
                int row = 16 * wq + q4 * 4 + r;
                int qrow = bq * 64 + row;
                out[((size_t)b * 2048 + qrow) * 128 + 16 * dt + l16] =
                    (oacc[dt][r] + Om[row * 128 + 16 * dt + l16]) * inv[r];
            }
        }
    }
}

extern "C" void kernel_launch(void* const* d_in, const int* in_sizes, int n_in,
                              void* d_out, int out_size, void* d_ws, size_t ws_size,
                              hipStream_t stream) {
    const float* query = (const float*)d_in[0];
    const float* key   = (const float*)d_in[1];
    const float* value = (const float*)d_in[2];
    const float* Wq    = (const float*)d_in[3];
    const float* bq    = (const float*)d_in[4];
    const float* Wk    = (const float*)d_in[5];
    const float* bk    = (const float*)d_in[6];
    const float* Wv    = (const float*)d_in[7];
    const float* bv    = (const float*)d_in[8];
    float* out = (float*)d_out;

    // ws layout (shorts): wtf[3][32][8][64][8] | q[16384][128] | k[16384][128] | vt[8][128][2048]
    short* wtf = (short*)d_ws;
    short* qws = wtf + 3 * 131072;
    short* kws = qws + 16384 * 128;
    short* vws = kws + 16384 * 128;

    wconv_kernel<<<1536, 256, 0, stream>>>(Wq, Wk, Wv, wtf);
    proj_kernel<<<dim3(256, 3), 256, 0, stream>>>(query, key, value, wtf,
                                                  bq, bk, bv, qws, kws, vws);
    flash_kernel<<<256, 512, 0, stream>>>(qws, kws, vws, out);
}